// Round 5
// baseline (299.739 us; speedup 1.0000x reference)
//
#include <hip/hip_runtime.h>

// Problem constants (fixed by the reference):
#define B_ 8
#define S_ 8192
#define D_ 768
#define V_ 64
#define L_ 26

typedef __attribute__((ext_vector_type(8))) short short8;   // 8 bf16 (4 VGPRs)
typedef __attribute__((ext_vector_type(4))) float floatx4;  // MFMA C/D

#define TOKS 512               // tokens (K) per block
#define SLICES (S_ / TOKS)     // 16 K-slices -> partial-sum planes
#define WNSL 32                // d-columns per wave (2 tiles of 16)
#define BCOLS 128              // d-columns per block (4 waves)
#define KSTEPS (TOKS / 32)     // 16

// sums[b] = OneHot(ids[b])^T @ H[b] via bf16 MFMA (exact one-hot A,
// hi/lo-split B). Register-double-buffered K-loop: ALL of step k+1's
// global loads (ids + 16 H dwords/lane) issue before step k is consumed,
// so each wave keeps a full step of misses in flight instead of
// serializing 8-load groups on s_waitcnt. 3 blocks/CU (12 waves).
// grid = (16, 6, 8) = 768 blocks.
__global__ __launch_bounds__(256, 3) void pool_mfma_kernel(
    const float* __restrict__ h, const int* __restrict__ ids,
    float* __restrict__ part, unsigned int* __restrict__ cntpart)
{
    __shared__ unsigned int cnt[V_];

    const int tid  = threadIdx.x;
    const int lane = tid & 63;
    const int wave = tid >> 6;
    const int nl   = lane & 15;   // n (B) / m (A) index within a 16-tile
    const int quad = lane >> 4;   // k-quadrant: lane covers k = quad*8 + j

    const int b     = blockIdx.z;
    const int slice = blockIdx.x;
    const int k0    = slice * TOKS;
    const int n0    = blockIdx.y * BCOLS + wave * WNSL;

    const int*   idrow = ids + b * S_ + k0;
    const float* hrow  = h + ((size_t)b * S_ + k0) * D_ + n0;

    // Per-slice histogram (y==0 plane only; non-atomic flush).
    if (blockIdx.y == 0) {
        if (tid < V_) cnt[tid] = 0u;
        __syncthreads();
        if (tid < TOKS / 4) {
            const int4 q = ((const int4*)idrow)[tid];
            atomicAdd(&cnt[q.x], 1u); atomicAdd(&cnt[q.y], 1u);
            atomicAdd(&cnt[q.z], 1u); atomicAdd(&cnt[q.w], 1u);
        }
        __syncthreads();
        if (tid < V_) cntpart[(slice * B_ + b) * V_ + tid] = cnt[tid];
    }

    floatx4 acc[4][2];
    #pragma unroll
    for (int mt = 0; mt < 4; ++mt)
        #pragma unroll
        for (int nt = 0; nt < 2; ++nt) acc[mt][nt] = (floatx4)0.f;

    // ---- register double buffers ----
    int4  idA0, idA1, idB0, idB1;
    float fA[2][8], fB[2][8];

    // issue all loads of step `m` into one buffer (no waits implied here)
    auto load_step = [&](int m, int4& i0, int4& i1, float f[2][8]) {
        const int kb = m * 32 + quad * 8;
        const int4* ip = (const int4*)(idrow + kb);
        i0 = ip[0]; i1 = ip[1];
        const float* bp = hrow + (size_t)kb * D_ + nl;
        #pragma unroll
        for (int t = 0; t < 2; ++t)
            #pragma unroll
            for (int j = 0; j < 8; ++j)
                f[t][j] = bp[(size_t)j * D_ + t * 16];
    };

    // consume one buffer: build one-hot A, hi/lo-split B, 16 MFMAs
    auto compute_step = [&](const int4& i0, const int4& i1,
                            const float f[2][8]) {
        const int idv[8] = {i0.x, i0.y, i0.z, i0.w, i1.x, i1.y, i1.z, i1.w};
        short8 afrag[4];
        #pragma unroll
        for (int mt = 0; mt < 4; ++mt) {
            const int m = mt * 16 + nl;
            #pragma unroll
            for (int j = 0; j < 8; ++j)
                afrag[mt][j] = (idv[j] == m) ? (short)0x3F80 : (short)0;
        }
        #pragma unroll
        for (int t = 0; t < 2; ++t) {
            short8 bhi, blo;
            #pragma unroll
            for (int j = 0; j < 8; ++j) {
                const unsigned u = __builtin_bit_cast(unsigned, f[t][j]);
                bhi[j] = (short)(u >> 16);
                const float hif = __builtin_bit_cast(float, u & 0xFFFF0000u);
                const float lof = f[t][j] - hif;
                blo[j] = (short)(__builtin_bit_cast(unsigned, lof) >> 16);
            }
            #pragma unroll
            for (int mt = 0; mt < 4; ++mt) {
                acc[mt][t] = __builtin_amdgcn_mfma_f32_16x16x32_bf16(
                    afrag[mt], bhi, acc[mt][t], 0, 0, 0);
                acc[mt][t] = __builtin_amdgcn_mfma_f32_16x16x32_bf16(
                    afrag[mt], blo, acc[mt][t], 0, 0, 0);
            }
        }
    };

    // ---- ping-pong pipeline: loads for k+1 in flight while computing k ----
    load_step(0, idA0, idA1, fA);
    for (int ks = 0; ks < KSTEPS; ks += 2) {
        load_step(ks + 1, idB0, idB1, fB);          // B in flight
        compute_step(idA0, idA1, fA);               // consume A
        if (ks + 2 < KSTEPS) load_step(ks + 2, idA0, idA1, fA);  // A in flight
        compute_step(idB0, idB1, fB);               // consume B
    }

    // Flush partial sums (plain stores). C/D: col=lane&15, row=quad*4+r.
    float* pbase = part + ((size_t)(slice * B_ + b) * V_) * D_;
    #pragma unroll
    for (int mt = 0; mt < 4; ++mt)
        #pragma unroll
        for (int nt = 0; nt < 2; ++nt)
            #pragma unroll
            for (int r = 0; r < 4; ++r) {
                const int v = mt * 16 + quad * 4 + r;
                const int d = n0 + nt * 16 + nl;
                pbase[(size_t)v * D_ + d] = acc[mt][nt][r];
            }
}

// Reduce 16 partial planes, mean, classify (26 dots of length 768), mask.
// One block (4 waves) per (batch, symbol) row.
__global__ __launch_bounds__(256) void reduce_finalize_kernel(
    const float* __restrict__ part, const unsigned int* __restrict__ cntpart,
    const float* __restrict__ Wm, const float* __restrict__ bias,
    float* __restrict__ out)
{
    __shared__ float mean[D_];
    __shared__ unsigned int scnt;

    const int tid = threadIdx.x;
    const int bv  = blockIdx.x;
    const int b   = bv >> 6;
    const int v   = bv & (V_ - 1);

    if (tid == 0) scnt = 0u;
    __syncthreads();
    if (tid < SLICES)
        atomicAdd(&scnt, cntpart[(tid * B_ + b) * V_ + v]);

    float s[3];
    #pragma unroll
    for (int j = 0; j < 3; ++j) {
        const int d = tid + j * 256;
        float a = 0.f;
        #pragma unroll
        for (int sl = 0; sl < SLICES; ++sl)
            a += part[((size_t)(sl * B_ + b) * V_ + v) * D_ + d];
        s[j] = a;
    }
    __syncthreads();               // scnt complete
    const unsigned int c = scnt;
    const float inv = 1.f / (float)(c > 1u ? c : 1u);
    #pragma unroll
    for (int j = 0; j < 3; ++j) mean[tid + j * 256] = s[j] * inv;
    __syncthreads();               // means visible

    const bool present = (c > 0u) && (v > 0);
    const int lane = tid & 63;
    const int wave = tid >> 6;
    for (int l = wave; l < L_; l += 4) {
        const float* wrow = Wm + l * D_;
        float p = 0.f;
        #pragma unroll
        for (int j = 0; j < 12; ++j) {
            const int d = lane + 64 * j;
            p += mean[d] * wrow[d];
        }
        #pragma unroll
        for (int off = 32; off > 0; off >>= 1) p += __shfl_down(p, off);
        if (lane == 0) out[bv * L_ + l] = present ? (p + bias[l]) : 0.f;
    }
}

extern "C" void kernel_launch(void* const* d_in, const int* in_sizes, int n_in,
                              void* d_out, int out_size, void* d_ws, size_t ws_size,
                              hipStream_t stream) {
    // setup_inputs order: hidden_states, W, b, input_ids
    const float* h    = (const float*)d_in[0];
    const float* Wm   = (const float*)d_in[1];
    const float* bias = (const float*)d_in[2];
    const int*   ids  = (const int*)d_in[3];
    float* out = (float*)d_out;

    // Workspace: [SLICES][B][V][D] fp32 partial sums, [SLICES][B][V] u32 counts.
    // Every element is written before being read -> no zero-init needed.
    float* part = (float*)d_ws;
    unsigned int* cntpart =
        (unsigned int*)(part + (size_t)SLICES * B_ * V_ * D_);

    dim3 grid1(SLICES, D_ / BCOLS, B_);   // (16, 6, 8) = 768 blocks
    pool_mfma_kernel<<<grid1, 256, 0, stream>>>(h, ids, part, cntpart);

    reduce_finalize_kernel<<<B_ * V_, 256, 0, stream>>>(
        part, cntpart, Wm, bias, out);
}

// Round 6
// 299.074 us; speedup vs baseline: 1.0022x; 1.0022x over previous
//
#include <hip/hip_runtime.h>

// Problem constants (fixed by the reference):
#define B_ 8
#define S_ 8192
#define D_ 768
#define V_ 64
#define L_ 26

typedef __attribute__((ext_vector_type(8)))  short short8;    // 8 bf16
typedef __attribute__((ext_vector_type(16))) float floatx16;  // 32x32 MFMA C/D

#define TOKS 512               // tokens (K) per block
#define SLICES (S_ / TOKS)     // 16 K-slice planes
#define BCOLS 128              // d-columns per block
#define KT 64                  // tokens per LDS tile (32 KB)
#define NTILES (TOKS / KT)     // 8

// sums[b] = OneHot(ids[b])^T @ H[b] via 32x32x16 bf16 MFMA (exact one-hot A,
// hi/lo-split B). H staged global->LDS with global_load_lds width=16:
// 1 KB/wave per outstanding instruction (4x byte depth of dword loads),
// no VGPR round trip. [k][128] LDS layout is lane-contiguous for the
// staging deposit AND conflict-free (2-way) for 32-wide B-fragment reads.
// grid = (16, 6, 8) = 768 blocks, 4 blocks/CU.
__global__ __launch_bounds__(256, 4) void pool_mfma_kernel(
    const float* __restrict__ h, const int* __restrict__ ids,
    float* __restrict__ part, unsigned int* __restrict__ cntpart)
{
    __shared__ float tile[KT * BCOLS];   // 32 KB
    __shared__ unsigned int cnt[V_];

    const int tid   = threadIdx.x;
    const int lane  = tid & 63;
    const int wave  = tid >> 6;
    const int nn    = lane & 31;   // n (B) / m (A) index within a 32-tile
    const int khalf = lane >> 5;   // k-half: lane covers k = khalf*8 + j

    const int b     = blockIdx.z;
    const int slice = blockIdx.x;
    const int k0    = slice * TOKS;
    const int n0blk = blockIdx.y * BCOLS;
    const int nw    = wave * 32;   // wave's column slab within the block

    const int* idrow = ids + b * S_ + k0;

    // Per-slice histogram (y==0 plane only; branch is block-uniform).
    if (blockIdx.y == 0) {
        if (tid < V_) cnt[tid] = 0u;
        __syncthreads();
        if (tid < TOKS / 4) {
            const int4 q = ((const int4*)idrow)[tid];
            atomicAdd(&cnt[q.x], 1u); atomicAdd(&cnt[q.y], 1u);
            atomicAdd(&cnt[q.z], 1u); atomicAdd(&cnt[q.w], 1u);
        }
        __syncthreads();
        if (tid < V_) cntpart[(slice * B_ + b) * V_ + tid] = cnt[tid];
    }

    floatx16 acc[2];
    acc[0] = (floatx16)0.f;
    acc[1] = (floatx16)0.f;

    const char* gblk = (const char*)(h + ((size_t)(b * S_ + k0) * D_ + n0blk));
    // staging: lane l -> row +(l>>5), col 4*(l&31); deposit = base + 16*l
    const size_t lane_off = (size_t)(lane >> 5) * (D_ * 4) + (size_t)(lane & 31) * 16;
    const int r0 = wave * 16;      // wave stages rows r0..r0+15 of each tile

    for (int t = 0; t < NTILES; ++t) {
        const char* gtile = gblk + (size_t)(t * KT) * (D_ * 4);
        #pragma unroll
        for (int i = 0; i < 8; ++i) {
            const int r = r0 + 2 * i;                       // rows r, r+1
            const char* gp = gtile + (size_t)r * (D_ * 4) + lane_off;
            __builtin_amdgcn_global_load_lds(
                (const __attribute__((address_space(1))) unsigned int*)gp,
                (__attribute__((address_space(3))) unsigned int*)&tile[r * BCOLS],
                16, 0, 0);
        }
        __syncthreads();

        #pragma unroll
        for (int ss = 0; ss < KT / 16; ++ss) {              // 4 K=16 steps
            const int kb = ss * 16 + khalf * 8;             // k base within tile
            // this lane's 8 token ids (two aligned int4, L1-broadcast)
            const int4 i0 = *(const int4*)(idrow + t * KT + kb);
            const int4 i1 = *(const int4*)(idrow + t * KT + kb + 4);
            const int idv[8] = {i0.x, i0.y, i0.z, i0.w, i1.x, i1.y, i1.z, i1.w};

            // one-hot A (exact in bf16): A[m = mt*32+nn][k = khalf*8+j]
            short8 af[2];
            #pragma unroll
            for (int mt = 0; mt < 2; ++mt) {
                const int m = mt * 32 + nn;
                #pragma unroll
                for (int j = 0; j < 8; ++j)
                    af[mt][j] = (idv[j] == m) ? (short)0x3F80 : (short)0;
            }

            // B fragment from LDS: B[k][n=nw+nn]; banks = nn -> 2-way (free)
            float f[8];
            #pragma unroll
            for (int j = 0; j < 8; ++j)
                f[j] = tile[(kb + j) * BCOLS + nw + nn];

            short8 bhi, blo;
            #pragma unroll
            for (int j = 0; j < 8; ++j) {
                const unsigned u = __builtin_bit_cast(unsigned, f[j]);
                bhi[j] = (short)(u >> 16);
                const float hif = __builtin_bit_cast(float, u & 0xFFFF0000u);
                const float lof = f[j] - hif;
                blo[j] = (short)(__builtin_bit_cast(unsigned, lof) >> 16);
            }

            #pragma unroll
            for (int mt = 0; mt < 2; ++mt) {
                acc[mt] = __builtin_amdgcn_mfma_f32_32x32x16_bf16(
                    af[mt], bhi, acc[mt], 0, 0, 0);
                acc[mt] = __builtin_amdgcn_mfma_f32_32x32x16_bf16(
                    af[mt], blo, acc[mt], 0, 0, 0);
            }
        }
        __syncthreads();
    }

    // Flush partials (plain stores, coalesced along d).
    // 32x32 C/D layout: col = lane&31, row = (r&3) + 8*(r>>2) + 4*(lane>>5).
    float* pbase = part + (size_t)(slice * B_ + b) * V_ * D_;
    const int d = n0blk + nw + nn;
    #pragma unroll
    for (int mt = 0; mt < 2; ++mt)
        #pragma unroll
        for (int r = 0; r < 16; ++r) {
            const int v = mt * 32 + (r & 3) + 8 * (r >> 2) + 4 * khalf;
            pbase[(size_t)v * D_ + d] = acc[mt][r];
        }
}

// Reduce 16 partial planes, mean, classify (26 dots of length 768), mask.
// One block (4 waves) per (batch, symbol) row.
__global__ __launch_bounds__(256) void reduce_finalize_kernel(
    const float* __restrict__ part, const unsigned int* __restrict__ cntpart,
    const float* __restrict__ Wm, const float* __restrict__ bias,
    float* __restrict__ out)
{
    __shared__ float mean[D_];
    __shared__ unsigned int scnt;

    const int tid = threadIdx.x;
    const int bv  = blockIdx.x;
    const int b   = bv >> 6;
    const int v   = bv & (V_ - 1);

    if (tid == 0) scnt = 0u;
    __syncthreads();
    if (tid < SLICES)
        atomicAdd(&scnt, cntpart[(tid * B_ + b) * V_ + v]);

    float s[3];
    #pragma unroll
    for (int j = 0; j < 3; ++j) {
        const int d = tid + j * 256;
        float a = 0.f;
        #pragma unroll
        for (int sl = 0; sl < SLICES; ++sl)
            a += part[((size_t)(sl * B_ + b) * V_ + v) * D_ + d];
        s[j] = a;
    }
    __syncthreads();               // scnt complete
    const unsigned int c = scnt;
    const float inv = 1.f / (float)(c > 1u ? c : 1u);
    #pragma unroll
    for (int j = 0; j < 3; ++j) mean[tid + j * 256] = s[j] * inv;
    __syncthreads();               // means visible

    const bool present = (c > 0u) && (v > 0);
    const int lane = tid & 63;
    const int wave = tid >> 6;
    for (int l = wave; l < L_; l += 4) {
        const float* wrow = Wm + l * D_;
        float p = 0.f;
        #pragma unroll
        for (int j = 0; j < 12; ++j) {
            const int d = lane + 64 * j;
            p += mean[d] * wrow[d];
        }
        #pragma unroll
        for (int off = 32; off > 0; off >>= 1) p += __shfl_down(p, off);
        if (lane == 0) out[bv * L_ + l] = present ? (p + bias[l]) : 0.f;
    }
}

extern "C" void kernel_launch(void* const* d_in, const int* in_sizes, int n_in,
                              void* d_out, int out_size, void* d_ws, size_t ws_size,
                              hipStream_t stream) {
    // setup_inputs order: hidden_states, W, b, input_ids
    const float* h    = (const float*)d_in[0];
    const float* Wm   = (const float*)d_in[1];
    const float* bias = (const float*)d_in[2];
    const int*   ids  = (const int*)d_in[3];
    float* out = (float*)d_out;

    // Workspace: [SLICES][B][V][D] fp32 partial sums, [SLICES][B][V] u32 counts.
    // Every element is written before being read -> no zero-init needed.
    float* part = (float*)d_ws;
    unsigned int* cntpart =
        (unsigned int*)(part + (size_t)SLICES * B_ * V_ * D_);

    dim3 grid1(SLICES, D_ / BCOLS, B_);   // (16, 6, 8) = 768 blocks
    pool_mfma_kernel<<<grid1, 256, 0, stream>>>(h, ids, part, cntpart);

    reduce_finalize_kernel<<<B_ * V_, 256, 0, stream>>>(
        part, cntpart, Wm, bias, out);
}